// Round 4
// baseline (231.331 us; speedup 1.0000x reference)
//
#include <hip/hip_runtime.h>
#include <hip/hip_bf16.h>

typedef __bf16 bf16;
typedef __attribute__((ext_vector_type(8))) __bf16 bf16x8;
typedef __attribute__((ext_vector_type(4))) float f32x4;

#define NBLK 256  // radix chunks == scanA block size (bucket-aligned scan)

// unpack 8 packed bf16 (uint4) -> two f32x4
__device__ inline void unpack8(uint4 r, f32x4& a, f32x4& b) {
  a.x = __uint_as_float(r.x << 16);
  a.y = __uint_as_float(r.x & 0xffff0000u);
  a.z = __uint_as_float(r.y << 16);
  a.w = __uint_as_float(r.y & 0xffff0000u);
  b.x = __uint_as_float(r.z << 16);
  b.y = __uint_as_float(r.z & 0xffff0000u);
  b.z = __uint_as_float(r.w << 16);
  b.w = __uint_as_float(r.w & 0xffff0000u);
}

// predicated 8-rows-per-wave slot load: slot q = lane>>3, 8 lanes cover a 128 B row
__device__ inline uint4 slot_load(const bf16* __restrict__ tab, const int* __restrict__ nbr,
                                  int base, int e, int q, int fo) {
  int idx = base + q;
  uint4 r = make_uint4(0u, 0u, 0u, 0u);
  if (idx < e) {
    int j = nbr[idx];
    r = *(const uint4*)(tab + j * 64 + fo);
  }
  return r;
}

// Fused setup: blocks [0,NBLK) histogram; [NBLK,NBLK+128) pack B1/B2; rest cvt x->xb.
__global__ __launch_bounds__(256) void setup_k(const float* __restrict__ x,
                                               const int* __restrict__ dst,
                                               const float* __restrict__ W1l,
                                               const float* __restrict__ W1r,
                                               const float* __restrict__ W2l,
                                               const float* __restrict__ W2r,
                                               bf16* __restrict__ xb,
                                               bf16* __restrict__ B1,
                                               bf16* __restrict__ B2,
                                               int* __restrict__ hist,
                                               int E, int nb, int N, int Np) {
  __shared__ int h[1024];
  int t = threadIdx.x;
  if (blockIdx.x < NBLK) {
    // per-chunk LDS histogram -> hist[bucket * NBLK + chunk]
    for (int i = t; i < nb; i += 256) h[i] = 0;
    __syncthreads();
    int chunk = (E + NBLK - 1) / NBLK;
    int s = blockIdx.x * chunk, e = min(E, s + chunk);
    for (int i = s + t; i < e; i += 256) atomicAdd(&h[dst[i] >> 7], 1);
    __syncthreads();
    for (int i = t; i < nb; i += 256) hist[(long)i * NBLK + blockIdx.x] = h[i];
  } else if (blockIdx.x < NBLK + 128) {
    int gid = (blockIdx.x - NBLK) * 256 + t;  // 0..32767
    if (gid < 16384) {
      int c = gid >> 7, k = gid & 127;
      float v = (k < 64) ? W1l[c * 64 + k] : W1r[c * 64 + (k - 64)];
      B1[gid] = (bf16)v;
    } else {
      int idx = gid - 16384;
      int n = idx >> 7, k = idx & 127;
      float v = (n < 64) ? W2l[n * 128 + k] : W2r[(n - 64) * 128 + k];
      B2[idx] = (bf16)v;
    }
  } else {
    int gid = (blockIdx.x - NBLK - 128) * 256 + t;  // one per 4 elems
    long base = (long)gid * 4;
    if (base >= (long)Np * 64) return;
    if (base < (long)N * 64) {
      f32x4 v = *(const f32x4*)(x + base);
      bf16 o[4] = {(bf16)v.x, (bf16)v.y, (bf16)v.z, (bf16)v.w};
      *(ulong1*)(xb + base) = *(ulong1*)o;
    } else {
      bf16 o[4] = {(bf16)0.0f, (bf16)0.0f, (bf16)0.0f, (bf16)0.0f};
      *(ulong1*)(xb + base) = *(ulong1*)o;
    }
  }
}

// scanA: one block per bucket; exclusive scan of the bucket's 256 chunk counts
// in place; bucket total -> bsum[bucket].
__global__ __launch_bounds__(256) void scanA_k(int* __restrict__ hist,
                                               int* __restrict__ bsum) {
  __shared__ int sd[256];
  int t = threadIdx.x;
  int idx = blockIdx.x * 256 + t;
  int v = hist[idx];
  sd[t] = v;
  __syncthreads();
#pragma unroll
  for (int off = 1; off < 256; off <<= 1) {
    int tv = (t >= off) ? sd[t - off] : 0;
    __syncthreads();
    if (t >= off) sd[t] += tv;
    __syncthreads();
  }
  hist[idx] = sd[t] - v;  // bucket-local exclusive prefix
  if (t == 255) bsum[blockIdx.x] = sd[255];
}

// scanB: single-block in-place exclusive scan of bsum (nb <= 1024).
// Afterwards bsum[b] = global start offset of bucket b.
__global__ __launch_bounds__(1024) void scanB_k(int* __restrict__ bsum, int nb) {
  __shared__ int sd[1024];
  int t = threadIdx.x;
  int v = (t < nb) ? bsum[t] : 0;
  sd[t] = v;
  __syncthreads();
#pragma unroll
  for (int off = 1; off < 1024; off <<= 1) {
    int tv = (t >= off) ? sd[t - off] : 0;
    __syncthreads();
    if (t >= off) sd[t] += tv;
    __syncthreads();
  }
  if (t < nb) bsum[t] = sd[t] - v;
}

// Pass 2: re-read chunk, LDS cursors = bsum[b] + hist[b][chunk], write packed
// records (src<<7 | local-dst) into bucket regions.
__global__ __launch_bounds__(512) void scat_k(const int* __restrict__ src,
                                              const int* __restrict__ dst,
                                              const int* __restrict__ hist,
                                              const int* __restrict__ bsum,
                                              unsigned* __restrict__ ebuf, int E, int nb) {
  __shared__ int cur[1024];
  for (int i = threadIdx.x; i < nb; i += 512)
    cur[i] = bsum[i] + hist[(long)i * NBLK + blockIdx.x];
  __syncthreads();
  int chunk = (E + NBLK - 1) / NBLK;
  int s = blockIdx.x * chunk, e = min(E, s + chunk);
  for (int i = s + threadIdx.x; i < e; i += 512) {
    int d = dst[i];
    int pos = atomicAdd(&cur[d >> 7], 1);
    ebuf[pos] = ((unsigned)src[i] << 7) | (unsigned)(d & 127);
  }
}

// per-bucket LDS counting sort -> node-ordered nbr + rowptr.
__global__ __launch_bounds__(256) void csr_k(const unsigned* __restrict__ ebuf,
                                             const int* __restrict__ bsum,
                                             int* __restrict__ rowptr,
                                             int* __restrict__ nbr, int nb, int Np, int E) {
  __shared__ int hcnt[128];
  __shared__ int hoff[128];
  int b = blockIdx.x, t = threadIdx.x;
  int s = bsum[b];
  int e = (b + 1 < nb) ? bsum[b + 1] : E;
  if (t < 128) hcnt[t] = 0;
  __syncthreads();
  for (int i = s + t; i < e; i += 256) atomicAdd(&hcnt[ebuf[i] & 127u], 1);
  __syncthreads();
  if (t < 128) hoff[t] = hcnt[t];
  __syncthreads();
#pragma unroll
  for (int off = 1; off < 128; off <<= 1) {
    int v = (t < 128 && t >= off) ? hoff[t - off] : 0;
    __syncthreads();
    if (t < 128 && t >= off) hoff[t] += v;
    __syncthreads();
  }
  if (t < 128) {
    int ex = hoff[t] - hcnt[t];  // exclusive scan
    rowptr[b * 128 + t] = s + ex;
    hcnt[t] = ex;  // becomes relative cursor
  }
  if (blockIdx.x == gridDim.x - 1 && t == 0) rowptr[Np] = E;
  __syncthreads();
  for (int i = s + t; i < e; i += 256) {
    unsigned r = ebuf[i];
    int pos = atomicAdd(&hcnt[r & 127u], 1);
    nbr[s + pos] = (int)(r >> 7);
  }
}

// ---- layer 1 aggregation, v2: 4 nodes per wave, interleaved gather loads ----
// R3 rationale: wave-per-node had only 2 outstanding 16B gather loads per wave
// (avg degree 12 fits in the c0/c1 pair) -> latency-bound at ~30% HBM, VALU 47%.
// 4 nodes/wave issues 8+ independent gathers back-to-back before any unpack:
// ~4x in-flight bytes per wave. Degree>16 tails stay per-node (rare, ~10%).
// All arrays statically indexed (unrolled) to stay in registers.
__global__ __launch_bounds__(256) void agg1_k(const bf16* __restrict__ xb,
                                              const int* __restrict__ rowptr,
                                              const int* __restrict__ nbr,
                                              bf16* __restrict__ A1, int Np) {
  int wave = threadIdx.x >> 6, lane = threadIdx.x & 63;
  int n0 = (blockIdx.x * 4 + wave) * 4;
  if (n0 >= Np) return;
  int q = lane >> 3, f = lane & 7;
  int fo = f * 8;  // 8 features per lane (16 B)
  int s[4], e[4];
#pragma unroll
  for (int m = 0; m < 4; m++) { s[m] = rowptr[n0 + m]; e[m] = rowptr[n0 + m + 1]; }
  uint4 c0[4], c1[4], rv[4];
#pragma unroll
  for (int m = 0; m < 4; m++) {
    c0[m] = slot_load(xb, nbr, s[m], e[m], q, fo);
    c1[m] = slot_load(xb, nbr, s[m] + 8, e[m], q, fo);
  }
#pragma unroll
  for (int m = 0; m < 4; m++)
    rv[m] = (q == 1) ? *(const uint4*)(xb + (long)(n0 + m) * 64 + fo)
                     : make_uint4(0u, 0u, 0u, 0u);
  f32x4 sa[4], sb[4];
#pragma unroll
  for (int m = 0; m < 4; m++) { sa[m] = f32x4{0, 0, 0, 0}; sb[m] = f32x4{0, 0, 0, 0}; }
#pragma unroll
  for (int m = 0; m < 4; m++) {
    if (s[m] + 16 < e[m]) {  // rare long-degree tail, depth-2 pipelined
      uint4 a0 = c0[m], a1 = c1[m];
      for (int i = s[m] + 16; i < e[m]; i += 16) {
        uint4 t0 = slot_load(xb, nbr, i, e[m], q, fo);
        uint4 t1 = slot_load(xb, nbr, i + 8, e[m], q, fo);
        f32x4 a, b;
        unpack8(a0, a, b); sa[m] += a; sb[m] += b;
        unpack8(a1, a, b); sa[m] += a; sb[m] += b;
        a0 = t0; a1 = t1;
      }
      c0[m] = a0; c1[m] = a1;
    }
    f32x4 a, b;
    unpack8(c0[m], a, b); sa[m] += a; sb[m] += b;
    unpack8(c1[m], a, b); sa[m] += a; sb[m] += b;
  }
#pragma unroll
  for (int m = 0; m < 4; m++) {
    float v[8] = {sa[m].x, sa[m].y, sa[m].z, sa[m].w, sb[m].x, sb[m].y, sb[m].z, sb[m].w};
#pragma unroll
    for (int k = 0; k < 8; k++) {
      v[k] += __shfl_xor(v[k], 8);
      v[k] += __shfl_xor(v[k], 16);
      v[k] += __shfl_xor(v[k], 32);
    }
    int n = n0 + m;
    float invd = 1.0f / fmaxf((float)(e[m] - s[m]), 1.0f);
    if (q == 0) {
      bf16x8 o = {(bf16)(v[0] * invd), (bf16)(v[1] * invd), (bf16)(v[2] * invd),
                  (bf16)(v[3] * invd), (bf16)(v[4] * invd), (bf16)(v[5] * invd),
                  (bf16)(v[6] * invd), (bf16)(v[7] * invd)};
      *(bf16x8*)(A1 + (long)n * 128 + fo) = o;
    } else if (q == 1) {
      *(uint4*)(A1 + (long)n * 128 + 64 + fo) = rv[m];  // pads: xb==0
    }
  }
}

// ---- fused GEMM1+GEMM2, v3: register-persistent B + grid-stride row tiles ----
// R2 rationale: R0/R1 were L2-latency serialized (VGPR=64 -> 1-2 loads in
// flight; every B fragment re-fetched from L2 per tile; MfmaUtil ~4%).
// Fix: each wave owns 32 output cols; its 16 B1/B2 fragments (64 VGPRs) are
// loaded ONCE and stay in registers across a grid-stride loop over 32-row
// tiles. A-tiles double-buffered in LDS (reg-staged: loads issued at loop
// top, ds_write after stores -> HBM latency hides under both GEMMs). h goes
// through LDS for the cross-wave K exchange. 256 B LDS rows would be 16-way
// bank-conflicted (G4), so A and h use XOR swizzle x^=((r&3)<<6)^((r&7)<<4)
// on the inner byte offset, write+read both swizzled (rule 21): <=4-way.
__device__ inline int swzoff(int r, int x) {
  return r * 256 + (x ^ (((r & 3) << 6) ^ ((r & 7) << 4)));
}

__global__ __launch_bounds__(256) void fused_k(const bf16* __restrict__ A,
                                               const bf16* __restrict__ B1g,
                                               const bf16* __restrict__ B2g,
                                               const float* __restrict__ b1l,
                                               bf16* __restrict__ Ct,
                                               bf16* __restrict__ Cu, int T) {
  __shared__ __align__(16) char Asm[2][8192];  // 32 rows x 256 B, double-buffered
  __shared__ __align__(16) char Hsm[8192];     // 32 rows x 256 B
  int tid = threadIdx.x;
  int wave = tid >> 6, lane = tid & 63;
  int row = lane & 15, quad = lane >> 4;
  int cb = wave * 32;  // this wave's 32 output cols

  // persistent B fragments: B row = output col (cb+jj*16+row), k = s*32+quad*8
  bf16x8 b1f[2][4], b2f[2][4];
#pragma unroll
  for (int jj = 0; jj < 2; jj++)
#pragma unroll
    for (int s = 0; s < 4; s++) {
      b1f[jj][s] = *(const bf16x8*)(B1g + (cb + jj * 16 + row) * 128 + s * 32 + quad * 8);
      b2f[jj][s] = *(const bf16x8*)(B2g + (cb + jj * 16 + row) * 128 + s * 32 + quad * 8);
    }
  float bias[2] = {b1l[cb + row], b1l[cb + 16 + row]};

  // A staging: per wave 2 x uint4 -> 8 rows; lane covers (row srow+ii*4+quad, chunk)
  int srow = wave * 8 + quad;
  int schunk = row;  // 16 B chunk index within the 256 B row

  int t = blockIdx.x;
  {  // prologue: stage tile t into buf 0
    uint4 v0 = *(const uint4*)(A + ((long)t * 32 + srow) * 128 + schunk * 8);
    uint4 v1 = *(const uint4*)(A + ((long)t * 32 + srow + 4) * 128 + schunk * 8);
    *(uint4*)(Asm[0] + swzoff(srow, schunk * 16)) = v0;
    *(uint4*)(Asm[0] + swzoff(srow + 4, schunk * 16)) = v1;
  }
  __syncthreads();

  int p = 0;
  for (; t < T; t += (int)gridDim.x, p ^= 1) {
    int tn = t + (int)gridDim.x;
    bool pf = tn < T;
    uint4 v0 = {}, v1 = {};
    if (pf) {  // issue next-tile loads now; consumed after the stores
      v0 = *(const uint4*)(A + ((long)tn * 32 + srow) * 128 + schunk * 8);
      v1 = *(const uint4*)(A + ((long)tn * 32 + srow + 4) * 128 + schunk * 8);
    }
    // ---- GEMM1: 32 rows x 32 cols, K=128, A from LDS, B1 from regs ----
    f32x4 acc1[2][2] = {};
#pragma unroll
    for (int s = 0; s < 4; s++) {
#pragma unroll
      for (int st = 0; st < 2; st++) {
        bf16x8 a = *(const bf16x8*)(Asm[p] + swzoff(st * 16 + row, s * 64 + quad * 16));
#pragma unroll
        for (int jj = 0; jj < 2; jj++)
          acc1[st][jj] = __builtin_amdgcn_mfma_f32_16x16x32_bf16(a, b1f[jj][s], acc1[st][jj], 0, 0, 0);
      }
    }
    // epilogue 1: bias+relu -> Hsm (C/D: row-in-tile=quad*4+i, col=cb+jj*16+row)
#pragma unroll
    for (int st = 0; st < 2; st++)
#pragma unroll
      for (int jj = 0; jj < 2; jj++)
#pragma unroll
        for (int i = 0; i < 4; i++) {
          float v = acc1[st][jj][i] + bias[jj];
          v = v > 0.0f ? v : 0.0f;
          *(bf16*)(Hsm + swzoff(st * 16 + quad * 4 + i, (cb + jj * 16 + row) * 2)) = (bf16)v;
        }
    __syncthreads();  // h visible to all waves (K exchange)
    // ---- GEMM2: 32 rows x 32 cols, K=128, h from LDS, B2 from regs ----
    f32x4 acc2[2][2] = {};
#pragma unroll
    for (int s = 0; s < 4; s++) {
#pragma unroll
      for (int st = 0; st < 2; st++) {
        bf16x8 a = *(const bf16x8*)(Hsm + swzoff(st * 16 + row, s * 64 + quad * 16));
#pragma unroll
        for (int jj = 0; jj < 2; jj++)
          acc2[st][jj] = __builtin_amdgcn_mfma_f32_16x16x32_bf16(a, b2f[jj][s], acc2[st][jj], 0, 0, 0);
      }
    }
    // epilogue 2: waves 0,1 -> Ct cols 0..63; waves 2,3 -> Cu cols 0..63
    bf16* outp = (wave < 2) ? Ct : Cu;
    int oc = cb + row - ((wave < 2) ? 0 : 64);
#pragma unroll
    for (int st = 0; st < 2; st++)
#pragma unroll
      for (int jj = 0; jj < 2; jj++)
#pragma unroll
        for (int i = 0; i < 4; i++) {
          long grow = (long)t * 32 + st * 16 + quad * 4 + i;
          outp[grow * 64 + oc + jj * 16] = (bf16)acc2[st][jj][i];
        }
    if (pf) {  // stage next tile into the other buffer
      *(uint4*)(Asm[p ^ 1] + swzoff(srow, schunk * 16)) = v0;
      *(uint4*)(Asm[p ^ 1] + swzoff(srow + 4, schunk * 16)) = v1;
    }
    __syncthreads();  // A(t+1) visible; also fences h reads vs next h writes
  }
}

// ---- layer 2 aggregation, v2: 4 nodes per wave (same R3 rationale as agg1) ----
__global__ __launch_bounds__(256) void agg2_k(const bf16* __restrict__ tmat,
                                              const bf16* __restrict__ umat,
                                              const int* __restrict__ rowptr,
                                              const int* __restrict__ nbr,
                                              const float* __restrict__ b2l,
                                              float* __restrict__ out, int N) {
  int wave = threadIdx.x >> 6, lane = threadIdx.x & 63;
  int n0 = (blockIdx.x * 4 + wave) * 4;
  if (n0 >= N) return;
  int q = lane >> 3, f = lane & 7;
  int fo = f * 8;
  int s[4], e[4];
#pragma unroll
  for (int m = 0; m < 4; m++) {
    int n = n0 + m;
    bool ok = n < N;
    s[m] = ok ? rowptr[n] : 0;
    e[m] = ok ? rowptr[n + 1] : 0;
  }
  uint4 c0[4], c1[4], um[4];
#pragma unroll
  for (int m = 0; m < 4; m++) {
    c0[m] = slot_load(tmat, nbr, s[m], e[m], q, fo);
    c1[m] = slot_load(tmat, nbr, s[m] + 8, e[m], q, fo);
  }
#pragma unroll
  for (int m = 0; m < 4; m++)
    um[m] = (q == 0 && n0 + m < N) ? *(const uint4*)(umat + (long)(n0 + m) * 64 + fo)
                                   : make_uint4(0u, 0u, 0u, 0u);
  f32x4 b0 = *(const f32x4*)(b2l + fo);
  f32x4 b1 = *(const f32x4*)(b2l + fo + 4);
  f32x4 sa[4], sb[4];
#pragma unroll
  for (int m = 0; m < 4; m++) { sa[m] = f32x4{0, 0, 0, 0}; sb[m] = f32x4{0, 0, 0, 0}; }
#pragma unroll
  for (int m = 0; m < 4; m++) {
    if (s[m] + 16 < e[m]) {  // rare long-degree tail
      uint4 a0 = c0[m], a1 = c1[m];
      for (int i = s[m] + 16; i < e[m]; i += 16) {
        uint4 t0 = slot_load(tmat, nbr, i, e[m], q, fo);
        uint4 t1 = slot_load(tmat, nbr, i + 8, e[m], q, fo);
        f32x4 a, b;
        unpack8(a0, a, b); sa[m] += a; sb[m] += b;
        unpack8(a1, a, b); sa[m] += a; sb[m] += b;
        a0 = t0; a1 = t1;
      }
      c0[m] = a0; c1[m] = a1;
    }
    f32x4 a, b;
    unpack8(c0[m], a, b); sa[m] += a; sb[m] += b;
    unpack8(c1[m], a, b); sa[m] += a; sb[m] += b;
  }
#pragma unroll
  for (int m = 0; m < 4; m++) {
    float v[8] = {sa[m].x, sa[m].y, sa[m].z, sa[m].w, sb[m].x, sb[m].y, sb[m].z, sb[m].w};
#pragma unroll
    for (int k = 0; k < 8; k++) {
      v[k] += __shfl_xor(v[k], 8);
      v[k] += __shfl_xor(v[k], 16);
      v[k] += __shfl_xor(v[k], 32);
    }
    int n = n0 + m;
    if (q == 0 && n < N) {
      float invd = 1.0f / fmaxf((float)(e[m] - s[m]), 1.0f);
      f32x4 ua, ub;
      unpack8(um[m], ua, ub);
      f32x4 o0, o1;
      o0.x = v[0] * invd + b0.x + ua.x;
      o0.y = v[1] * invd + b0.y + ua.y;
      o0.z = v[2] * invd + b0.z + ua.z;
      o0.w = v[3] * invd + b0.w + ua.w;
      o1.x = v[4] * invd + b1.x + ub.x;
      o1.y = v[5] * invd + b1.y + ub.y;
      o1.z = v[6] * invd + b1.z + ub.z;
      o1.w = v[7] * invd + b1.w + ub.w;
      *(f32x4*)(out + (long)n * 64 + fo) = o0;
      *(f32x4*)(out + (long)n * 64 + fo + 4) = o1;
    }
  }
}

static inline size_t align256(size_t x) { return (x + 255) / 256 * 256; }

extern "C" void kernel_launch(void* const* d_in, const int* in_sizes, int n_in,
                              void* d_out, int out_size, void* d_ws, size_t ws_size,
                              hipStream_t stream) {
  const float* x = (const float*)d_in[0];
  const int* edge_index = (const int*)d_in[1];
  const float* W1l = (const float*)d_in[2];
  const float* b1l = (const float*)d_in[3];
  const float* W1r = (const float*)d_in[4];
  const float* W2l = (const float*)d_in[5];
  const float* b2l = (const float*)d_in[6];
  const float* W2r = (const float*)d_in[7];

  const int N = in_sizes[0] / 64;        // 100000
  const int E = in_sizes[1] / 2;         // 1200000
  const int Np = (N + 127) / 128 * 128;  // 100096
  const int nb = Np / 128;               // 782 buckets (<=1024 for scanB)
  const int M = nb * NBLK;               // hist elements (200192)

  const int* src = edge_index;
  const int* dst = edge_index + E;

  // ws layout (~75 MB; must not alias: fused_k reads A1 while writing tmat/umat)
  char* ws = (char*)d_ws;
  size_t off = 0;
  int* hist = (int*)(ws + off);           off += align256((size_t)M * 4);
  int* bsum = (int*)(ws + off);           off += align256((size_t)nb * 4);
  int* rowptr = (int*)(ws + off);         off += align256((size_t)(Np + 1) * 4);
  unsigned* ebuf = (unsigned*)(ws + off); off += align256((size_t)E * 4);
  int* nbr = (int*)(ws + off);            off += align256((size_t)E * 4);
  bf16* xb = (bf16*)(ws + off);           off += align256((size_t)Np * 64 * 2);
  bf16* A1 = (bf16*)(ws + off);           off += align256((size_t)Np * 128 * 2);
  bf16* tmat = (bf16*)(ws + off);         off += align256((size_t)Np * 64 * 2);
  bf16* umat = (bf16*)(ws + off);         off += align256((size_t)Np * 64 * 2);
  bf16* B1 = (bf16*)(ws + off);           off += align256(128 * 128 * 2);
  bf16* B2 = (bf16*)(ws + off);           off += align256(128 * 128 * 2);
  float* out = (float*)d_out;

  const int cvtBlocks = (int)(((long)Np * 64 / 4 + 255) / 256);
  setup_k<<<NBLK + 128 + cvtBlocks, 256, 0, stream>>>(x, dst, W1l, W1r, W2l, W2r,
                                                      xb, B1, B2, hist, E, nb, N, Np);
  scanA_k<<<nb, 256, 0, stream>>>(hist, bsum);
  scanB_k<<<1, 1024, 0, stream>>>(bsum, nb);
  scat_k<<<NBLK, 512, 0, stream>>>(src, dst, hist, bsum, ebuf, E, nb);
  csr_k<<<nb, 256, 0, stream>>>(ebuf, bsum, rowptr, nbr, nb, Np, E);

  agg1_k<<<Np / 16, 256, 0, stream>>>(xb, rowptr, nbr, A1, Np);
  fused_k<<<1024, 256, 0, stream>>>(A1, B1, B2, b1l, tmat, umat, Np / 32);
  agg2_k<<<(N + 15) / 16, 256, 0, stream>>>(tmat, umat, rowptr, nbr, b2l, out, N);
}

// Round 5
// 219.632 us; speedup vs baseline: 1.0533x; 1.0533x over previous
//
#include <hip/hip_runtime.h>
#include <hip/hip_bf16.h>

typedef __bf16 bf16;
typedef __attribute__((ext_vector_type(8))) __bf16 bf16x8;
typedef __attribute__((ext_vector_type(4))) float f32x4;

#define NBLK 256  // radix chunks == scanA block size (bucket-aligned scan)

// unpack 8 packed bf16 (uint4) -> two f32x4
__device__ inline void unpack8(uint4 r, f32x4& a, f32x4& b) {
  a.x = __uint_as_float(r.x << 16);
  a.y = __uint_as_float(r.x & 0xffff0000u);
  a.z = __uint_as_float(r.y << 16);
  a.w = __uint_as_float(r.y & 0xffff0000u);
  b.x = __uint_as_float(r.z << 16);
  b.y = __uint_as_float(r.z & 0xffff0000u);
  b.z = __uint_as_float(r.w << 16);
  b.w = __uint_as_float(r.w & 0xffff0000u);
}

// predicated 8-rows-per-wave slot load: slot q = lane>>3, 8 lanes cover a 128 B row
__device__ inline uint4 slot_load(const bf16* __restrict__ tab, const int* __restrict__ nbr,
                                  int base, int e, int q, int fo) {
  int idx = base + q;
  uint4 r = make_uint4(0u, 0u, 0u, 0u);
  if (idx < e) {
    int j = nbr[idx];
    r = *(const uint4*)(tab + j * 64 + fo);
  }
  return r;
}

// Fused setup: blocks [0,NBLK) histogram; [NBLK,NBLK+128) pack B1/B2; rest cvt x->xb.
__global__ __launch_bounds__(256) void setup_k(const float* __restrict__ x,
                                               const int* __restrict__ dst,
                                               const float* __restrict__ W1l,
                                               const float* __restrict__ W1r,
                                               const float* __restrict__ W2l,
                                               const float* __restrict__ W2r,
                                               bf16* __restrict__ xb,
                                               bf16* __restrict__ B1,
                                               bf16* __restrict__ B2,
                                               int* __restrict__ hist,
                                               int E, int nb, int N, int Np) {
  __shared__ int h[1024];
  int t = threadIdx.x;
  if (blockIdx.x < NBLK) {
    // per-chunk LDS histogram -> hist[bucket * NBLK + chunk]
    for (int i = t; i < nb; i += 256) h[i] = 0;
    __syncthreads();
    int chunk = (E + NBLK - 1) / NBLK;
    int s = blockIdx.x * chunk, e = min(E, s + chunk);
    for (int i = s + t; i < e; i += 256) atomicAdd(&h[dst[i] >> 7], 1);
    __syncthreads();
    for (int i = t; i < nb; i += 256) hist[(long)i * NBLK + blockIdx.x] = h[i];
  } else if (blockIdx.x < NBLK + 128) {
    int gid = (blockIdx.x - NBLK) * 256 + t;  // 0..32767
    if (gid < 16384) {
      int c = gid >> 7, k = gid & 127;
      float v = (k < 64) ? W1l[c * 64 + k] : W1r[c * 64 + (k - 64)];
      B1[gid] = (bf16)v;
    } else {
      int idx = gid - 16384;
      int n = idx >> 7, k = idx & 127;
      float v = (n < 64) ? W2l[n * 128 + k] : W2r[(n - 64) * 128 + k];
      B2[idx] = (bf16)v;
    }
  } else {
    int gid = (blockIdx.x - NBLK - 128) * 256 + t;  // one per 4 elems
    long base = (long)gid * 4;
    if (base >= (long)Np * 64) return;
    if (base < (long)N * 64) {
      f32x4 v = *(const f32x4*)(x + base);
      bf16 o[4] = {(bf16)v.x, (bf16)v.y, (bf16)v.z, (bf16)v.w};
      *(ulong1*)(xb + base) = *(ulong1*)o;
    } else {
      bf16 o[4] = {(bf16)0.0f, (bf16)0.0f, (bf16)0.0f, (bf16)0.0f};
      *(ulong1*)(xb + base) = *(ulong1*)o;
    }
  }
}

// scanA: one block per bucket; exclusive scan of the bucket's 256 chunk counts
// in place; bucket total -> bsum[bucket].
__global__ __launch_bounds__(256) void scanA_k(int* __restrict__ hist,
                                               int* __restrict__ bsum) {
  __shared__ int sd[256];
  int t = threadIdx.x;
  int idx = blockIdx.x * 256 + t;
  int v = hist[idx];
  sd[t] = v;
  __syncthreads();
#pragma unroll
  for (int off = 1; off < 256; off <<= 1) {
    int tv = (t >= off) ? sd[t - off] : 0;
    __syncthreads();
    if (t >= off) sd[t] += tv;
    __syncthreads();
  }
  hist[idx] = sd[t] - v;  // bucket-local exclusive prefix
  if (t == 255) bsum[blockIdx.x] = sd[255];
}

// scanB: single-block in-place exclusive scan of bsum (nb <= 1024).
// Afterwards bsum[b] = global start offset of bucket b.
__global__ __launch_bounds__(1024) void scanB_k(int* __restrict__ bsum, int nb) {
  __shared__ int sd[1024];
  int t = threadIdx.x;
  int v = (t < nb) ? bsum[t] : 0;
  sd[t] = v;
  __syncthreads();
#pragma unroll
  for (int off = 1; off < 1024; off <<= 1) {
    int tv = (t >= off) ? sd[t - off] : 0;
    __syncthreads();
    if (t >= off) sd[t] += tv;
    __syncthreads();
  }
  if (t < nb) bsum[t] = sd[t] - v;
}

// Pass 2: re-read chunk, LDS cursors = bsum[b] + hist[b][chunk], write packed
// records (src<<7 | local-dst) into bucket regions.
__global__ __launch_bounds__(512) void scat_k(const int* __restrict__ src,
                                              const int* __restrict__ dst,
                                              const int* __restrict__ hist,
                                              const int* __restrict__ bsum,
                                              unsigned* __restrict__ ebuf, int E, int nb) {
  __shared__ int cur[1024];
  for (int i = threadIdx.x; i < nb; i += 512)
    cur[i] = bsum[i] + hist[(long)i * NBLK + blockIdx.x];
  __syncthreads();
  int chunk = (E + NBLK - 1) / NBLK;
  int s = blockIdx.x * chunk, e = min(E, s + chunk);
  for (int i = s + threadIdx.x; i < e; i += 512) {
    int d = dst[i];
    int pos = atomicAdd(&cur[d >> 7], 1);
    ebuf[pos] = ((unsigned)src[i] << 7) | (unsigned)(d & 127);
  }
}

// per-bucket LDS counting sort -> node-ordered nbr + rowptr.
__global__ __launch_bounds__(256) void csr_k(const unsigned* __restrict__ ebuf,
                                             const int* __restrict__ bsum,
                                             int* __restrict__ rowptr,
                                             int* __restrict__ nbr, int nb, int Np, int E) {
  __shared__ int hcnt[128];
  __shared__ int hoff[128];
  int b = blockIdx.x, t = threadIdx.x;
  int s = bsum[b];
  int e = (b + 1 < nb) ? bsum[b + 1] : E;
  if (t < 128) hcnt[t] = 0;
  __syncthreads();
  for (int i = s + t; i < e; i += 256) atomicAdd(&hcnt[ebuf[i] & 127u], 1);
  __syncthreads();
  if (t < 128) hoff[t] = hcnt[t];
  __syncthreads();
#pragma unroll
  for (int off = 1; off < 128; off <<= 1) {
    int v = (t < 128 && t >= off) ? hoff[t - off] : 0;
    __syncthreads();
    if (t < 128 && t >= off) hoff[t] += v;
    __syncthreads();
  }
  if (t < 128) {
    int ex = hoff[t] - hcnt[t];  // exclusive scan
    rowptr[b * 128 + t] = s + ex;
    hcnt[t] = ex;  // becomes relative cursor
  }
  if (blockIdx.x == gridDim.x - 1 && t == 0) rowptr[Np] = E;
  __syncthreads();
  for (int i = s + t; i < e; i += 256) {
    unsigned r = ebuf[i];
    int pos = atomicAdd(&hcnt[r & 127u], 1);
    nbr[s + pos] = (int)(r >> 7);
  }
}

// ---- layer 1 aggregation, v3: 4 nodes/wave, cross-node depth-2 pipeline ----
// R5 rationale: R4's all-upfront 4-node batch needed ~100 live VGPRs; compiler
// reported 56 -> spilled/sank, occupancy crashed to 36% (scratch-limited) and
// dur regressed 41->58. This version bounds liveness: at iter m we issue node
// m+2's two gathers, then consume node m -> >=4 gathers in flight, <=6 uint4
// (24 VGPR) live. Accumulators are per-node scalars, root load pipelined
// depth-1. Expect VGPR ~90-130, no scratch.
__global__ __launch_bounds__(256) void agg1_k(const bf16* __restrict__ xb,
                                              const int* __restrict__ rowptr,
                                              const int* __restrict__ nbr,
                                              bf16* __restrict__ A1, int Np) {
  int wave = threadIdx.x >> 6, lane = threadIdx.x & 63;
  int n0 = (blockIdx.x * 4 + wave) * 4;
  if (n0 >= Np) return;
  int q = lane >> 3, f = lane & 7;
  int fo = f * 8;  // 8 features per lane (16 B)
  int s[4], e[4];
#pragma unroll
  for (int m = 0; m < 4; m++) { s[m] = rowptr[n0 + m]; e[m] = rowptr[n0 + m + 1]; }
  uint4 c0[4], c1[4];
#pragma unroll
  for (int m = 0; m < 2; m++) {
    c0[m] = slot_load(xb, nbr, s[m], e[m], q, fo);
    c1[m] = slot_load(xb, nbr, s[m] + 8, e[m], q, fo);
  }
  uint4 rvc = (q == 1) ? *(const uint4*)(xb + (long)n0 * 64 + fo)
                       : make_uint4(0u, 0u, 0u, 0u);
#pragma unroll
  for (int m = 0; m < 4; m++) {
    if (m + 2 < 4) {  // prefetch node m+2's gathers (static idx after unroll)
      c0[m + 2] = slot_load(xb, nbr, s[m + 2], e[m + 2], q, fo);
      c1[m + 2] = slot_load(xb, nbr, s[m + 2] + 8, e[m + 2], q, fo);
    }
    uint4 rvn = (q == 1 && m + 1 < 4)
                    ? *(const uint4*)(xb + (long)(n0 + m + 1) * 64 + fo)
                    : make_uint4(0u, 0u, 0u, 0u);
    f32x4 sa = {0, 0, 0, 0}, sb = {0, 0, 0, 0};
    uint4 a0 = c0[m], a1 = c1[m];
    if (s[m] + 16 < e[m]) {  // rare long-degree tail, depth-2 pipelined
      for (int i = s[m] + 16; i < e[m]; i += 16) {
        uint4 t0 = slot_load(xb, nbr, i, e[m], q, fo);
        uint4 t1 = slot_load(xb, nbr, i + 8, e[m], q, fo);
        f32x4 a, b;
        unpack8(a0, a, b); sa += a; sb += b;
        unpack8(a1, a, b); sa += a; sb += b;
        a0 = t0; a1 = t1;
      }
    }
    {
      f32x4 a, b;
      unpack8(a0, a, b); sa += a; sb += b;
      unpack8(a1, a, b); sa += a; sb += b;
    }
    float v[8] = {sa.x, sa.y, sa.z, sa.w, sb.x, sb.y, sb.z, sb.w};
#pragma unroll
    for (int k = 0; k < 8; k++) {
      v[k] += __shfl_xor(v[k], 8);
      v[k] += __shfl_xor(v[k], 16);
      v[k] += __shfl_xor(v[k], 32);
    }
    float invd = 1.0f / fmaxf((float)(e[m] - s[m]), 1.0f);
    if (q == 0) {
      bf16x8 o = {(bf16)(v[0] * invd), (bf16)(v[1] * invd), (bf16)(v[2] * invd),
                  (bf16)(v[3] * invd), (bf16)(v[4] * invd), (bf16)(v[5] * invd),
                  (bf16)(v[6] * invd), (bf16)(v[7] * invd)};
      *(bf16x8*)(A1 + (long)(n0 + m) * 128 + fo) = o;
    } else if (q == 1) {
      *(uint4*)(A1 + (long)(n0 + m) * 128 + 64 + fo) = rvc;  // pads: xb==0
    }
    rvc = rvn;
  }
}

// ---- fused GEMM1+GEMM2, v3: register-persistent B + grid-stride row tiles ----
// R2 rationale: R0/R1 were L2-latency serialized (VGPR=64 -> 1-2 loads in
// flight; every B fragment re-fetched from L2 per tile; MfmaUtil ~4%).
// Fix: each wave owns 32 output cols; its 16 B1/B2 fragments (64 VGPRs) are
// loaded ONCE and stay in registers across a grid-stride loop over 32-row
// tiles. A-tiles double-buffered in LDS (reg-staged: loads issued at loop
// top, ds_write after stores -> HBM latency hides under both GEMMs). h goes
// through LDS for the cross-wave K exchange. 256 B LDS rows would be 16-way
// bank-conflicted (G4), so A and h use XOR swizzle x^=((r&3)<<6)^((r&7)<<4)
// on the inner byte offset, write+read both swizzled (rule 21): <=4-way.
__device__ inline int swzoff(int r, int x) {
  return r * 256 + (x ^ (((r & 3) << 6) ^ ((r & 7) << 4)));
}

__global__ __launch_bounds__(256) void fused_k(const bf16* __restrict__ A,
                                               const bf16* __restrict__ B1g,
                                               const bf16* __restrict__ B2g,
                                               const float* __restrict__ b1l,
                                               bf16* __restrict__ Ct,
                                               bf16* __restrict__ Cu, int T) {
  __shared__ __align__(16) char Asm[2][8192];  // 32 rows x 256 B, double-buffered
  __shared__ __align__(16) char Hsm[8192];     // 32 rows x 256 B
  int tid = threadIdx.x;
  int wave = tid >> 6, lane = tid & 63;
  int row = lane & 15, quad = lane >> 4;
  int cb = wave * 32;  // this wave's 32 output cols

  // persistent B fragments: B row = output col (cb+jj*16+row), k = s*32+quad*8
  bf16x8 b1f[2][4], b2f[2][4];
#pragma unroll
  for (int jj = 0; jj < 2; jj++)
#pragma unroll
    for (int s = 0; s < 4; s++) {
      b1f[jj][s] = *(const bf16x8*)(B1g + (cb + jj * 16 + row) * 128 + s * 32 + quad * 8);
      b2f[jj][s] = *(const bf16x8*)(B2g + (cb + jj * 16 + row) * 128 + s * 32 + quad * 8);
    }
  float bias[2] = {b1l[cb + row], b1l[cb + 16 + row]};

  // A staging: per wave 2 x uint4 -> 8 rows; lane covers (row srow+ii*4+quad, chunk)
  int srow = wave * 8 + quad;
  int schunk = row;  // 16 B chunk index within the 256 B row

  int t = blockIdx.x;
  {  // prologue: stage tile t into buf 0
    uint4 v0 = *(const uint4*)(A + ((long)t * 32 + srow) * 128 + schunk * 8);
    uint4 v1 = *(const uint4*)(A + ((long)t * 32 + srow + 4) * 128 + schunk * 8);
    *(uint4*)(Asm[0] + swzoff(srow, schunk * 16)) = v0;
    *(uint4*)(Asm[0] + swzoff(srow + 4, schunk * 16)) = v1;
  }
  __syncthreads();

  int p = 0;
  for (; t < T; t += (int)gridDim.x, p ^= 1) {
    int tn = t + (int)gridDim.x;
    bool pf = tn < T;
    uint4 v0 = {}, v1 = {};
    if (pf) {  // issue next-tile loads now; consumed after the stores
      v0 = *(const uint4*)(A + ((long)tn * 32 + srow) * 128 + schunk * 8);
      v1 = *(const uint4*)(A + ((long)tn * 32 + srow + 4) * 128 + schunk * 8);
    }
    // ---- GEMM1: 32 rows x 32 cols, K=128, A from LDS, B1 from regs ----
    f32x4 acc1[2][2] = {};
#pragma unroll
    for (int s = 0; s < 4; s++) {
#pragma unroll
      for (int st = 0; st < 2; st++) {
        bf16x8 a = *(const bf16x8*)(Asm[p] + swzoff(st * 16 + row, s * 64 + quad * 16));
#pragma unroll
        for (int jj = 0; jj < 2; jj++)
          acc1[st][jj] = __builtin_amdgcn_mfma_f32_16x16x32_bf16(a, b1f[jj][s], acc1[st][jj], 0, 0, 0);
      }
    }
    // epilogue 1: bias+relu -> Hsm (C/D: row-in-tile=quad*4+i, col=cb+jj*16+row)
#pragma unroll
    for (int st = 0; st < 2; st++)
#pragma unroll
      for (int jj = 0; jj < 2; jj++)
#pragma unroll
        for (int i = 0; i < 4; i++) {
          float v = acc1[st][jj][i] + bias[jj];
          v = v > 0.0f ? v : 0.0f;
          *(bf16*)(Hsm + swzoff(st * 16 + quad * 4 + i, (cb + jj * 16 + row) * 2)) = (bf16)v;
        }
    __syncthreads();  // h visible to all waves (K exchange)
    // ---- GEMM2: 32 rows x 32 cols, K=128, h from LDS, B2 from regs ----
    f32x4 acc2[2][2] = {};
#pragma unroll
    for (int s = 0; s < 4; s++) {
#pragma unroll
      for (int st = 0; st < 2; st++) {
        bf16x8 a = *(const bf16x8*)(Hsm + swzoff(st * 16 + row, s * 64 + quad * 16));
#pragma unroll
        for (int jj = 0; jj < 2; jj++)
          acc2[st][jj] = __builtin_amdgcn_mfma_f32_16x16x32_bf16(a, b2f[jj][s], acc2[st][jj], 0, 0, 0);
      }
    }
    // epilogue 2: waves 0,1 -> Ct cols 0..63; waves 2,3 -> Cu cols 0..63
    bf16* outp = (wave < 2) ? Ct : Cu;
    int oc = cb + row - ((wave < 2) ? 0 : 64);
#pragma unroll
    for (int st = 0; st < 2; st++)
#pragma unroll
      for (int jj = 0; jj < 2; jj++)
#pragma unroll
        for (int i = 0; i < 4; i++) {
          long grow = (long)t * 32 + st * 16 + quad * 4 + i;
          outp[grow * 64 + oc + jj * 16] = (bf16)acc2[st][jj][i];
        }
    if (pf) {  // stage next tile into the other buffer
      *(uint4*)(Asm[p ^ 1] + swzoff(srow, schunk * 16)) = v0;
      *(uint4*)(Asm[p ^ 1] + swzoff(srow + 4, schunk * 16)) = v1;
    }
    __syncthreads();  // A(t+1) visible; also fences h reads vs next h writes
  }
}

// ---- layer 2 aggregation, v3: 4 nodes/wave, cross-node depth-2 pipeline ----
// (same R5 rationale as agg1_k)
__global__ __launch_bounds__(256) void agg2_k(const bf16* __restrict__ tmat,
                                              const bf16* __restrict__ umat,
                                              const int* __restrict__ rowptr,
                                              const int* __restrict__ nbr,
                                              const float* __restrict__ b2l,
                                              float* __restrict__ out, int N) {
  int wave = threadIdx.x >> 6, lane = threadIdx.x & 63;
  int n0 = (blockIdx.x * 4 + wave) * 4;
  if (n0 >= N) return;
  int q = lane >> 3, f = lane & 7;
  int fo = f * 8;
  int s[4], e[4];
#pragma unroll
  for (int m = 0; m < 4; m++) {
    int n = n0 + m;
    bool ok = n < N;
    s[m] = ok ? rowptr[n] : 0;
    e[m] = ok ? rowptr[n + 1] : 0;
  }
  uint4 c0[4], c1[4];
#pragma unroll
  for (int m = 0; m < 2; m++) {
    c0[m] = slot_load(tmat, nbr, s[m], e[m], q, fo);
    c1[m] = slot_load(tmat, nbr, s[m] + 8, e[m], q, fo);
  }
  uint4 umc = (q == 0) ? *(const uint4*)(umat + (long)n0 * 64 + fo)
                       : make_uint4(0u, 0u, 0u, 0u);
  f32x4 b0 = *(const f32x4*)(b2l + fo);
  f32x4 b1 = *(const f32x4*)(b2l + fo + 4);
#pragma unroll
  for (int m = 0; m < 4; m++) {
    if (m + 2 < 4) {  // prefetch node m+2's gathers
      c0[m + 2] = slot_load(tmat, nbr, s[m + 2], e[m + 2], q, fo);
      c1[m + 2] = slot_load(tmat, nbr, s[m + 2] + 8, e[m + 2], q, fo);
    }
    uint4 umn = (q == 0 && m + 1 < 4 && n0 + m + 1 < N)
                    ? *(const uint4*)(umat + (long)(n0 + m + 1) * 64 + fo)
                    : make_uint4(0u, 0u, 0u, 0u);
    f32x4 sa = {0, 0, 0, 0}, sb = {0, 0, 0, 0};
    uint4 a0 = c0[m], a1 = c1[m];
    if (s[m] + 16 < e[m]) {  // rare long-degree tail
      for (int i = s[m] + 16; i < e[m]; i += 16) {
        uint4 t0 = slot_load(tmat, nbr, i, e[m], q, fo);
        uint4 t1 = slot_load(tmat, nbr, i + 8, e[m], q, fo);
        f32x4 a, b;
        unpack8(a0, a, b); sa += a; sb += b;
        unpack8(a1, a, b); sa += a; sb += b;
        a0 = t0; a1 = t1;
      }
    }
    {
      f32x4 a, b;
      unpack8(a0, a, b); sa += a; sb += b;
      unpack8(a1, a, b); sa += a; sb += b;
    }
    float v[8] = {sa.x, sa.y, sa.z, sa.w, sb.x, sb.y, sb.z, sb.w};
#pragma unroll
    for (int k = 0; k < 8; k++) {
      v[k] += __shfl_xor(v[k], 8);
      v[k] += __shfl_xor(v[k], 16);
      v[k] += __shfl_xor(v[k], 32);
    }
    int n = n0 + m;
    if (q == 0 && n < N) {
      float invd = 1.0f / fmaxf((float)(e[m] - s[m]), 1.0f);
      f32x4 ua, ub;
      unpack8(umc, ua, ub);
      f32x4 o0, o1;
      o0.x = v[0] * invd + b0.x + ua.x;
      o0.y = v[1] * invd + b0.y + ua.y;
      o0.z = v[2] * invd + b0.z + ua.z;
      o0.w = v[3] * invd + b0.w + ua.w;
      o1.x = v[4] * invd + b1.x + ub.x;
      o1.y = v[5] * invd + b1.y + ub.y;
      o1.z = v[6] * invd + b1.z + ub.z;
      o1.w = v[7] * invd + b1.w + ub.w;
      *(f32x4*)(out + (long)n * 64 + fo) = o0;
      *(f32x4*)(out + (long)n * 64 + fo + 4) = o1;
    }
    umc = umn;
  }
}

static inline size_t align256(size_t x) { return (x + 255) / 256 * 256; }

extern "C" void kernel_launch(void* const* d_in, const int* in_sizes, int n_in,
                              void* d_out, int out_size, void* d_ws, size_t ws_size,
                              hipStream_t stream) {
  const float* x = (const float*)d_in[0];
  const int* edge_index = (const int*)d_in[1];
  const float* W1l = (const float*)d_in[2];
  const float* b1l = (const float*)d_in[3];
  const float* W1r = (const float*)d_in[4];
  const float* W2l = (const float*)d_in[5];
  const float* b2l = (const float*)d_in[6];
  const float* W2r = (const float*)d_in[7];

  const int N = in_sizes[0] / 64;        // 100000
  const int E = in_sizes[1] / 2;         // 1200000
  const int Np = (N + 127) / 128 * 128;  // 100096
  const int nb = Np / 128;               // 782 buckets (<=1024 for scanB)
  const int M = nb * NBLK;               // hist elements (200192)

  const int* src = edge_index;
  const int* dst = edge_index + E;

  // ws layout (~75 MB; must not alias: fused_k reads A1 while writing tmat/umat)
  char* ws = (char*)d_ws;
  size_t off = 0;
  int* hist = (int*)(ws + off);           off += align256((size_t)M * 4);
  int* bsum = (int*)(ws + off);           off += align256((size_t)nb * 4);
  int* rowptr = (int*)(ws + off);         off += align256((size_t)(Np + 1) * 4);
  unsigned* ebuf = (unsigned*)(ws + off); off += align256((size_t)E * 4);
  int* nbr = (int*)(ws + off);            off += align256((size_t)E * 4);
  bf16* xb = (bf16*)(ws + off);           off += align256((size_t)Np * 64 * 2);
  bf16* A1 = (bf16*)(ws + off);           off += align256((size_t)Np * 128 * 2);
  bf16* tmat = (bf16*)(ws + off);         off += align256((size_t)Np * 64 * 2);
  bf16* umat = (bf16*)(ws + off);         off += align256((size_t)Np * 64 * 2);
  bf16* B1 = (bf16*)(ws + off);           off += align256(128 * 128 * 2);
  bf16* B2 = (bf16*)(ws + off);           off += align256(128 * 128 * 2);
  float* out = (float*)d_out;

  const int cvtBlocks = (int)(((long)Np * 64 / 4 + 255) / 256);
  setup_k<<<NBLK + 128 + cvtBlocks, 256, 0, stream>>>(x, dst, W1l, W1r, W2l, W2r,
                                                      xb, B1, B2, hist, E, nb, N, Np);
  scanA_k<<<nb, 256, 0, stream>>>(hist, bsum);
  scanB_k<<<1, 1024, 0, stream>>>(bsum, nb);
  scat_k<<<NBLK, 512, 0, stream>>>(src, dst, hist, bsum, ebuf, E, nb);
  csr_k<<<nb, 256, 0, stream>>>(ebuf, bsum, rowptr, nbr, nb, Np, E);

  agg1_k<<<Np / 16, 256, 0, stream>>>(xb, rowptr, nbr, A1, Np);
  fused_k<<<1024, 256, 0, stream>>>(A1, B1, B2, b1l, tmat, umat, Np / 32);
  agg2_k<<<(N + 15) / 16, 256, 0, stream>>>(tmat, umat, rowptr, nbr, b2l, out, N);
}